// Round 1
// baseline (4810.597 us; speedup 1.0000x reference)
//
#include <hip/hip_runtime.h>

#define B_ 8
#define N_ 1024
#define C_ 768
#define H_ 12
#define HD_ 64
#define NB_ 49
#define BH_ (B_ * H_)
#define SCALE_ 0.125f
#define ROWS_ 4

// ---------------------------------------------------------------------------
// K1: transpose rp_bucket (so the rpe_q gather rp[j,i] becomes a coalesced
//     row read rpt[i,j])
// ---------------------------------------------------------------------------
__global__ void irpe_rp_transpose_k(const int* __restrict__ rp, int* __restrict__ rpt) {
    __shared__ int tile[32][33];
    const int bx = blockIdx.x * 32, by = blockIdx.y * 32;
    const int tx = threadIdx.x, ty = threadIdx.y;  // block (32, 8)
#pragma unroll
    for (int r = 0; r < 32; r += 8)
        tile[ty + r][tx] = rp[(size_t)(by + ty + r) * N_ + bx + tx];
    __syncthreads();
#pragma unroll
    for (int r = 0; r < 32; r += 8)
        rpt[(size_t)(bx + ty + r) * N_ + by + tx] = tile[tx][ty + r];
}

// ---------------------------------------------------------------------------
// K2: RPE tables.
//   tk[bh, i, u] = q[b,i,h,:] . w_rpe_k[:, u]
//   tq[bh, j, u] = SCALE * (k[b,j,h,:] . w_rpe_q[:, u])
// ---------------------------------------------------------------------------
__global__ void irpe_rpe_tables_k(const float* __restrict__ q, const float* __restrict__ k,
                                  const float* __restrict__ w_rpe_q, const float* __restrict__ w_rpe_k,
                                  float* __restrict__ tk, float* __restrict__ tq) {
    const int bh = blockIdx.y, b = bh / H_, h = bh % H_;
    const int row0 = blockIdx.x * 4;
    __shared__ float qs[4][HD_], ks[4][HD_];
    const int t = threadIdx.x;  // 256
    {
        const int r = t >> 6, d = t & 63;
        const size_t gi = ((size_t)(b * N_ + row0 + r)) * C_ + h * HD_ + d;
        qs[r][d] = q[gi];
        ks[r][d] = k[gi];
    }
    __syncthreads();
    if (t < 4 * NB_) {
        const int r = t / NB_, u = t - r * NB_;
        float dk = 0.f, dq = 0.f;
#pragma unroll
        for (int d = 0; d < HD_; ++d) {
            dk = fmaf(qs[r][d], w_rpe_k[d * NB_ + u], dk);
            dq = fmaf(ks[r][d], w_rpe_q[d * NB_ + u], dq);
        }
        const size_t o = ((size_t)bh * N_ + row0 + r) * NB_ + u;
        tk[o] = dk;
        tq[o] = dq * SCALE_;
    }
}

// ---------------------------------------------------------------------------
// K3: logits + biases + softmax -> attn (written normalized).
// One block = one (bh, {i0, i0+256, i0+512, i0+768}). 256 threads, 4 j's each.
// ---------------------------------------------------------------------------
__global__ void irpe_attn_softmax_k(const float* __restrict__ q, const float* __restrict__ k,
                                    const float* __restrict__ tk, const float* __restrict__ tq,
                                    const int* __restrict__ rp, const int* __restrict__ rpt,
                                    float* __restrict__ attn) {
    const int bh = blockIdx.y, b = bh / H_, h = bh % H_;
    const int i0 = blockIdx.x;  // rows are i0 + r*256
    __shared__ float qs[ROWS_][HD_];
    __shared__ float tks[ROWS_][NB_];
    __shared__ float redm[ROWS_][4];
    __shared__ float reds[ROWS_][4];
    const int t = threadIdx.x;
    {
        const int r = t >> 6, d = t & 63;
        const int i = i0 + r * 256;
        qs[r][d] = q[((size_t)(b * N_ + i)) * C_ + h * HD_ + d];
        if (d < NB_) tks[r][d] = tk[((size_t)bh * N_ + i) * NB_ + d];
    }
    __syncthreads();

    float logit[ROWS_][4];
#pragma unroll
    for (int it = 0; it < 4; ++it) {
        const int j = t + it * 256;
        const float* kp = &k[((size_t)(b * N_ + j)) * C_ + h * HD_];
        float dot[ROWS_] = {0.f, 0.f, 0.f, 0.f};
#pragma unroll
        for (int d4 = 0; d4 < HD_; d4 += 4) {
            const float4 kv = *(const float4*)(kp + d4);
#pragma unroll
            for (int r = 0; r < ROWS_; ++r) {
                dot[r] += qs[r][d4] * kv.x + qs[r][d4 + 1] * kv.y +
                          qs[r][d4 + 2] * kv.z + qs[r][d4 + 3] * kv.w;
            }
        }
        const float* tqj = &tq[((size_t)bh * N_ + j) * NB_];
#pragma unroll
        for (int r = 0; r < ROWS_; ++r) {
            const size_t i = (size_t)(i0 + r * 256);
            const int bij = rp[i * N_ + j];   // bucket(i, j)
            const int bji = rpt[i * N_ + j];  // bucket(j, i)
            logit[r][it] = dot[r] * SCALE_ + tks[r][bij] + tqj[bji];
        }
    }

    // row max
    float mx[ROWS_];
#pragma unroll
    for (int r = 0; r < ROWS_; ++r) {
        float m = fmaxf(fmaxf(logit[r][0], logit[r][1]), fmaxf(logit[r][2], logit[r][3]));
#pragma unroll
        for (int o = 32; o > 0; o >>= 1) m = fmaxf(m, __shfl_down(m, o));
        mx[r] = m;
    }
    if ((t & 63) == 0) {
#pragma unroll
        for (int r = 0; r < ROWS_; ++r) redm[r][t >> 6] = mx[r];
    }
    __syncthreads();
    float rowmax[ROWS_];
#pragma unroll
    for (int r = 0; r < ROWS_; ++r)
        rowmax[r] = fmaxf(fmaxf(redm[r][0], redm[r][1]), fmaxf(redm[r][2], redm[r][3]));

    // exp + row sum
    float s[ROWS_];
#pragma unroll
    for (int r = 0; r < ROWS_; ++r) {
        float ss = 0.f;
#pragma unroll
        for (int it = 0; it < 4; ++it) {
            const float e = __expf(logit[r][it] - rowmax[r]);
            logit[r][it] = e;
            ss += e;
        }
#pragma unroll
        for (int o = 32; o > 0; o >>= 1) ss += __shfl_down(ss, o);
        s[r] = ss;
    }
    if ((t & 63) == 0) {
#pragma unroll
        for (int r = 0; r < ROWS_; ++r) reds[r][t >> 6] = s[r];
    }
    __syncthreads();
#pragma unroll
    for (int r = 0; r < ROWS_; ++r) {
        const float inv = 1.f / (reds[r][0] + reds[r][1] + reds[r][2] + reds[r][3]);
        float* ap = &attn[((size_t)bh * N_ + i0 + r * 256) * N_];
#pragma unroll
        for (int it = 0; it < 4; ++it) ap[t + it * 256] = logit[r][it] * inv;
    }
}

// ---------------------------------------------------------------------------
// K4: out_pre = attn @ v  +  bucket_sums @ w_rpe_v  (written in [B,N,C] layout)
// ---------------------------------------------------------------------------
__global__ void irpe_pv_k(const float* __restrict__ attn, const float* __restrict__ v,
                          const int* __restrict__ rp, const float* __restrict__ w_rpe_v,
                          float* __restrict__ pre) {
    const int bh = blockIdx.y, b = bh / H_, h = bh % H_;
    const int i0 = blockIdx.x;  // rows i0 + r*256
    __shared__ float arow[ROWS_][N_];          // 16 KB
    __shared__ float bucket[ROWS_][NB_];
    __shared__ float partial[ROWS_][4][HD_];   // 4 KB
    const int t = threadIdx.x;

    if (t < ROWS_ * NB_) bucket[t / NB_][t % NB_] = 0.f;
#pragma unroll
    for (int r = 0; r < ROWS_; ++r) {
        const float* ap = &attn[((size_t)bh * N_ + i0 + r * 256) * N_];
#pragma unroll
        for (int it = 0; it < 4; ++it) arow[r][t + it * 256] = ap[t + it * 256];
    }
    __syncthreads();

    // bucket segment sums
#pragma unroll
    for (int r = 0; r < ROWS_; ++r) {
        const size_t i = (size_t)(i0 + r * 256);
#pragma unroll
        for (int it = 0; it < 4; ++it) {
            const int j = t + it * 256;
            atomicAdd(&bucket[r][rp[i * N_ + j]], arow[r][j]);
        }
    }

    // PV: thread (g, d), g = j-group of 256, d = head dim
    const int d = t & 63, g = t >> 6;
    float acc[ROWS_] = {0.f, 0.f, 0.f, 0.f};
    const float* vp = &v[((size_t)(b * N_)) * C_ + h * HD_ + d];
    for (int jj = 0; jj < 256; ++jj) {
        const int j = g * 256 + jj;
        const float vv = vp[(size_t)j * C_];
#pragma unroll
        for (int r = 0; r < ROWS_; ++r) acc[r] += arow[r][j] * vv;
    }
#pragma unroll
    for (int r = 0; r < ROWS_; ++r) partial[r][g][d] = acc[r];
    __syncthreads();

    {
        const int r = t >> 6, dd = t & 63;
        float o = partial[r][0][dd] + partial[r][1][dd] + partial[r][2][dd] + partial[r][3][dd];
        float rv = 0.f;
#pragma unroll
        for (int u = 0; u < NB_; ++u) rv = fmaf(bucket[r][u], w_rpe_v[u * HD_ + dd], rv);
        pre[((size_t)(b * N_ + i0 + r * 256)) * C_ + h * HD_ + dd] = o + rv;
    }
}

// ---------------------------------------------------------------------------
// K5: projection GEMM: out[m,n] = sum_k pre[m,k] * proj_w[n,k] + bias[n]
//     M = B*N = 8192, N = K = C = 768. 64x64 tile, 4x4 micro-tile.
// ---------------------------------------------------------------------------
__global__ void irpe_proj_gemm_k(const float* __restrict__ A, const float* __restrict__ Bw,
                                 const float* __restrict__ bias, float* __restrict__ Cout) {
    const int bm = blockIdx.x * 64, bn = blockIdx.y * 64;
    __shared__ float As[16][64];  // [k][m]
    __shared__ float Bs[16][64];  // [k][n]
    const int t = threadIdx.x;
    const int lr = t >> 2;          // 0..63 tile row
    const int lc = (t & 3) * 4;     // 0,4,8,12 k offset
    const int tx = t & 15, ty = t >> 4;
    float acc[4][4] = {{0.f}};

    for (int kt = 0; kt < C_; kt += 16) {
        const float4 av = *(const float4*)&A[(size_t)(bm + lr) * C_ + kt + lc];
        const float4 bv = *(const float4*)&Bw[(size_t)(bn + lr) * C_ + kt + lc];
        As[lc + 0][lr] = av.x; As[lc + 1][lr] = av.y; As[lc + 2][lr] = av.z; As[lc + 3][lr] = av.w;
        Bs[lc + 0][lr] = bv.x; Bs[lc + 1][lr] = bv.y; Bs[lc + 2][lr] = bv.z; Bs[lc + 3][lr] = bv.w;
        __syncthreads();
#pragma unroll
        for (int kk = 0; kk < 16; ++kk) {
            const float4 a = *(const float4*)&As[kk][ty * 4];
            const float4 b = *(const float4*)&Bs[kk][tx * 4];
            const float ar[4] = {a.x, a.y, a.z, a.w};
            const float br[4] = {b.x, b.y, b.z, b.w};
#pragma unroll
            for (int r = 0; r < 4; ++r)
#pragma unroll
                for (int c = 0; c < 4; ++c) acc[r][c] = fmaf(ar[r], br[c], acc[r][c]);
        }
        __syncthreads();
    }
#pragma unroll
    for (int r = 0; r < 4; ++r) {
        const int row = bm + ty * 4 + r;
#pragma unroll
        for (int c = 0; c < 4; ++c) {
            const int col = bn + tx * 4 + c;
            Cout[(size_t)row * C_ + col] = acc[r][c] + bias[col];
        }
    }
}

// ---------------------------------------------------------------------------
extern "C" void kernel_launch(void* const* d_in, const int* in_sizes, int n_in,
                              void* d_out, int out_size, void* d_ws, size_t ws_size,
                              hipStream_t stream) {
    const float* q       = (const float*)d_in[0];
    const float* k       = (const float*)d_in[1];
    const float* v       = (const float*)d_in[2];
    const float* w_rpe_q = (const float*)d_in[3];
    const float* w_rpe_k = (const float*)d_in[4];
    const float* w_rpe_v = (const float*)d_in[5];
    const float* proj_w  = (const float*)d_in[6];
    const float* proj_b  = (const float*)d_in[7];
    const int*   rp      = (const int*)d_in[8];

    float* out  = (float*)d_out;                    // [B,N,C]
    float* attn = out + (size_t)B_ * N_ * C_;       // [B,H,N,N]

    char* ws = (char*)d_ws;
    float* tk  = (float*)ws; ws += (size_t)BH_ * N_ * NB_ * sizeof(float);
    float* tq  = (float*)ws; ws += (size_t)BH_ * N_ * NB_ * sizeof(float);
    float* pre = (float*)ws; ws += (size_t)B_ * N_ * C_ * sizeof(float);
    int*   rpt = (int*)ws;   ws += (size_t)N_ * N_ * sizeof(int);

    irpe_rp_transpose_k<<<dim3(32, 32), dim3(32, 8), 0, stream>>>(rp, rpt);
    irpe_rpe_tables_k<<<dim3(N_ / 4, BH_), 256, 0, stream>>>(q, k, w_rpe_q, w_rpe_k, tk, tq);
    irpe_attn_softmax_k<<<dim3(N_ / ROWS_, BH_), 256, 0, stream>>>(q, k, tk, tq, rp, rpt, attn);
    irpe_pv_k<<<dim3(N_ / ROWS_, BH_), 256, 0, stream>>>(attn, v, rp, w_rpe_v, pre);
    irpe_proj_gemm_k<<<dim3(8192 / 64, C_ / 64), 256, 0, stream>>>(pre, proj_w, proj_b, out);
}

// Round 2
// 1926.778 us; speedup vs baseline: 2.4967x; 2.4967x over previous
//
#include <hip/hip_runtime.h>

#define B_ 8
#define N_ 1024
#define C_ 768
#define H_ 12
#define HD_ 64
#define NB_ 49
#define BH_ (B_ * H_)
#define SCALE_ 0.125f

#define TI_ 32      // i-rows per block
#define TJ_ 128     // j-cols per chunk
#define NCH_ (N_ / TJ_)

// LDS float offsets (dynamic shared memory)
#define OFF_QS    0                    // [32][68]
#define OFF_TKS   2176                 // [32][50]
#define OFF_LUT   3776                 // 64 ints
#define OFF_MS    3840                 // [32]
#define OFF_INVS  3872                 // [32]
#define OFF_KBUF  3904                 // [128][64] (k / tq[49][132] / v, time-shared)
#define OFF_AROW  12096                // [32][132]   (pass B only)
#define OFF_BKT   16320                // [32][50]    (pass B only)
#define LDS_A_FLOATS 12096
#define LDS_B_FLOATS 17920

// ---------------------------------------------------------------------------
// K1: derive the 63-entry piecewise-index LUT from rp_bucket itself.
// rp[i,j] = (f(yi-yj)+3)*7 + (f(xi-xj)+3);  lut[d+31] = f(d)+3.
// row 0 gives d<=0, bottom-right corner row gives d>0.
// ---------------------------------------------------------------------------
__global__ void irpe_lut_k(const int* __restrict__ rp, int* __restrict__ lut) {
    const int t = threadIdx.x;
    if (t < 63) {
        const int d = t - 31;
        int v;
        if (d <= 0) v = rp[-d] - 21;                                   // rp[0][-d]
        else        v = rp[(size_t)(N_ - 1) * N_ + (N_ - 1) - d] - 21; // rp[1023][1023-d]
        lut[t] = v;
    }
}

// ---------------------------------------------------------------------------
// K2: RPE tables.
//   tk [bh, i, u]  = q[b,i,h,:] . w_rpe_k[:, u]                 ([BH][N][49])
//   tqT[bh, u, j]  = SCALE * (k[b,j,h,:] . w_rpe_q[:, u])       ([BH][49][N])
// ---------------------------------------------------------------------------
__global__ void irpe_rpe_tables_k(const float* __restrict__ q, const float* __restrict__ k,
                                  const float* __restrict__ w_rpe_q, const float* __restrict__ w_rpe_k,
                                  float* __restrict__ tk, float* __restrict__ tqT) {
    const int bh = blockIdx.y, b = bh / H_, h = bh % H_;
    const int row0 = blockIdx.x * 4;
    __shared__ float qs[4][HD_], ks[4][HD_];
    const int t = threadIdx.x;  // 256
    {
        const int r = t >> 6, d = t & 63;
        const size_t gi = ((size_t)(b * N_ + row0 + r)) * C_ + h * HD_ + d;
        qs[r][d] = q[gi];
        ks[r][d] = k[gi];
    }
    __syncthreads();
    if (t < 4 * NB_) {
        const int r = t / NB_, u = t - r * NB_;
        float dk = 0.f, dq = 0.f;
#pragma unroll
        for (int d = 0; d < HD_; ++d) {
            dk = fmaf(qs[r][d], w_rpe_k[d * NB_ + u], dk);
            dq = fmaf(ks[r][d], w_rpe_q[d * NB_ + u], dq);
        }
        tk[((size_t)bh * N_ + row0 + r) * NB_ + u] = dk;
        tqT[(((size_t)bh * NB_ + u) << 10) + row0 + r] = dq * SCALE_;
    }
}

// ---------------------------------------------------------------------------
// Fused attention, 2 sweeps.
//  PASS 0: logits (QK*scale + bias_k + bias_q) -> online rowmax/rowsum only.
//  PASS 1: recompute logits, e=exp(l-m)/S -> write attn, LDS bucket sums,
//          PV accumulate, + bucket @ w_rpe_v, write pre[B,N,C].
// Block: 256 threads, TI=32 rows, chunks of TJ=128 cols.
// QK thread map: ig=t>>5 (4 rows ig*4+r), jg=t&31 (4 cols jg*4+c).
// PV thread map: ih=t>>4 (2 rows),       dq=t&15 (4 dims dq*4..).
// ---------------------------------------------------------------------------
template <int PASS>
__global__ __launch_bounds__(256, 2) void irpe_attn_fused_k(
    const float* __restrict__ q, const float* __restrict__ k, const float* __restrict__ v,
    const float* __restrict__ tk, const float* __restrict__ tqT, const int* __restrict__ lut,
    float* __restrict__ m_arr, float* __restrict__ s_arr,
    float* __restrict__ attn, const float* __restrict__ w_rpe_v, float* __restrict__ pre) {
    extern __shared__ float smem[];
    float* qs    = smem + OFF_QS;    // [32][68]
    float* tks   = smem + OFF_TKS;   // [32][50]
    int*   lutS  = (int*)(smem + OFF_LUT);
    float* m_s   = smem + OFF_MS;
    float* inv_s = smem + OFF_INVS;
    float* kbuf  = smem + OFF_KBUF;  // [128][64] or tq[49][132] or v[128][64]
    float* arow  = smem + OFF_AROW;  // [32][132]
    float* bkt   = smem + OFF_BKT;   // [32][50]

    const int gid = blockIdx.x;
    const int bh = gid % BH_, itile = gid / BH_;
    const int b = bh / H_, h = bh % H_;
    const int i0 = itile * TI_;
    const int t = threadIdx.x;
    const int ig = t >> 5, jg = t & 31;

    const float* qg = q + (size_t)b * N_ * C_ + h * HD_;
    const float* kg = k + (size_t)b * N_ * C_ + h * HD_;
    const float* vg = v + (size_t)b * N_ * C_ + h * HD_;

    // ---- block-wide preloads ----
#pragma unroll
    for (int rep = 0; rep < 2; ++rep) {  // q tile: 32 rows x 16 float4
        const int flat = rep * 256 + t;
        const int row = flat >> 4, q4 = flat & 15;
        *(float4*)&qs[row * 68 + q4 * 4] = *(const float4*)&qg[((size_t)(i0 + row)) * C_ + q4 * 4];
    }
    {   // tk rows
        const int r2 = t >> 3;
        for (int uu = t & 7; uu < NB_; uu += 8)
            tks[r2 * 50 + uu] = tk[((size_t)bh * N_ + i0 + r2) * NB_ + uu];
    }
    if (t < 63) lutS[t] = lut[t];
    if (PASS == 1) {
        if (t < TI_) {
            m_s[t] = m_arr[(size_t)bh * N_ + i0 + t];
            inv_s[t] = 1.0f / s_arr[(size_t)bh * N_ + i0 + t];
        }
        for (int idx = t; idx < TI_ * 50; idx += 256) bkt[idx] = 0.f;
    }
    __syncthreads();

    // per-thread i geometry
    int yi[4], xi[4];
#pragma unroll
    for (int r = 0; r < 4; ++r) {
        const int i = i0 + ig * 4 + r;
        yi[r] = i >> 5; xi[r] = i & 31;
    }

    float m_run[4], s_run[4];
#pragma unroll
    for (int r = 0; r < 4; ++r) { m_run[r] = -1e30f; s_run[r] = 0.f; }

    float4 acc0 = {0.f, 0.f, 0.f, 0.f}, acc1 = {0.f, 0.f, 0.f, 0.f};
    const int ih = t >> 4, dq = t & 15;  // PV map

    for (int ch = 0; ch < NCH_; ++ch) {
        const int jc0 = ch * TJ_;
        // ---- stage k chunk (swizzled) ----
#pragma unroll
        for (int rep = 0; rep < 8; ++rep) {
            const int flat = rep * 256 + t;
            const int jl = flat >> 4, q4 = flat & 15;
            *(float4*)&kbuf[jl * 64 + ((q4 ^ ((jl >> 2) & 7)) << 2)] =
                *(const float4*)&kg[((size_t)(jc0 + jl)) * C_ + q4 * 4];
        }
        __syncthreads();

        // ---- QK micro-tile 4x4 ----
        float lg[4][4];
#pragma unroll
        for (int r = 0; r < 4; ++r)
#pragma unroll
            for (int c = 0; c < 4; ++c) lg[r][c] = 0.f;
        const int jb = jg * 4;
#pragma unroll 4
        for (int d4 = 0; d4 < 16; ++d4) {
            const int slot = ((d4 ^ (jg & 7)) << 2);
            const float4 kv0 = *(const float4*)&kbuf[(jb + 0) * 64 + slot];
            const float4 kv1 = *(const float4*)&kbuf[(jb + 1) * 64 + slot];
            const float4 kv2 = *(const float4*)&kbuf[(jb + 2) * 64 + slot];
            const float4 kv3 = *(const float4*)&kbuf[(jb + 3) * 64 + slot];
#pragma unroll
            for (int r = 0; r < 4; ++r) {
                const float4 qv = *(const float4*)&qs[(ig * 4 + r) * 68 + d4 * 4];
                lg[r][0] += qv.x * kv0.x + qv.y * kv0.y + qv.z * kv0.z + qv.w * kv0.w;
                lg[r][1] += qv.x * kv1.x + qv.y * kv1.y + qv.z * kv1.z + qv.w * kv1.w;
                lg[r][2] += qv.x * kv2.x + qv.y * kv2.y + qv.z * kv2.z + qv.w * kv2.w;
                lg[r][3] += qv.x * kv3.x + qv.y * kv3.y + qv.z * kv3.z + qv.w * kv3.w;
            }
        }
        __syncthreads();

        // ---- stage tq chunk into same buffer: [49][132] ----
        for (int idx = t; idx < NB_ * TJ_; idx += 256) {
            const int u = idx >> 7, jj = idx & 127;
            kbuf[u * 132 + jj] = tqT[(((size_t)bh * NB_ + u) << 10) + jc0 + jj];
        }
        __syncthreads();

        // ---- bias + softmax-stat / emit ----
        const int yj = (jc0 + jb) >> 5;
        const int xj0 = jb & 31;
#pragma unroll
        for (int r = 0; r < 4; ++r) {
            float e4[4];
            int bij4[4];
#pragma unroll
            for (int c = 0; c < 4; ++c) {
                const int bij = lutS[yi[r] - yj + 31] * 7 + lutS[xi[r] - (xj0 + c) + 31];
                const int bji = lutS[yj - yi[r] + 31] * 7 + lutS[(xj0 + c) - xi[r] + 31];
                lg[r][c] = lg[r][c] * SCALE_ + tks[(ig * 4 + r) * 50 + bij] + kbuf[bji * 132 + jb + c];
                bij4[c] = bij;
            }
            if (PASS == 0) {
                const float mc = fmaxf(fmaxf(lg[r][0], lg[r][1]), fmaxf(lg[r][2], lg[r][3]));
                if (mc > m_run[r]) {
                    s_run[r] *= __expf(m_run[r] - mc);
                    m_run[r] = mc;
                }
                s_run[r] += __expf(lg[r][0] - m_run[r]) + __expf(lg[r][1] - m_run[r]) +
                            __expf(lg[r][2] - m_run[r]) + __expf(lg[r][3] - m_run[r]);
            } else {
                const int i = i0 + ig * 4 + r;
                const float mi = m_s[ig * 4 + r], si = inv_s[ig * 4 + r];
#pragma unroll
                for (int c = 0; c < 4; ++c) {
                    e4[c] = __expf(lg[r][c] - mi) * si;
                    atomicAdd(&bkt[(ig * 4 + r) * 50 + bij4[c]], e4[c]);
                }
                const float4 ev = {e4[0], e4[1], e4[2], e4[3]};
                *(float4*)&arow[(ig * 4 + r) * 132 + jb] = ev;
                *(float4*)&attn[(((size_t)bh << 10) + i) * N_ + jc0 + jb] = ev;
            }
        }
        __syncthreads();

        if (PASS == 1) {
            // ---- stage v chunk (swizzled, same buffer) ----
#pragma unroll
            for (int rep = 0; rep < 8; ++rep) {
                const int flat = rep * 256 + t;
                const int jl = flat >> 4, q4 = flat & 15;
                *(float4*)&kbuf[jl * 64 + ((q4 ^ ((jl >> 2) & 7)) << 2)] =
                    *(const float4*)&vg[((size_t)(jc0 + jl)) * C_ + q4 * 4];
            }
            __syncthreads();

            // ---- PV from arow x v ----
#pragma unroll 4
            for (int jq = 0; jq < 32; ++jq) {
                const float4 e0 = *(const float4*)&arow[(ih * 2 + 0) * 132 + jq * 4];
                const float4 e1 = *(const float4*)&arow[(ih * 2 + 1) * 132 + jq * 4];
                const float ea0[4] = {e0.x, e0.y, e0.z, e0.w};
                const float ea1[4] = {e1.x, e1.y, e1.z, e1.w};
#pragma unroll
                for (int c = 0; c < 4; ++c) {
                    const int jl = jq * 4 + c;
                    const float4 vv = *(const float4*)&kbuf[jl * 64 + ((dq ^ (jq & 7)) << 2)];
                    acc0.x += ea0[c] * vv.x; acc0.y += ea0[c] * vv.y;
                    acc0.z += ea0[c] * vv.z; acc0.w += ea0[c] * vv.w;
                    acc1.x += ea1[c] * vv.x; acc1.y += ea1[c] * vv.y;
                    acc1.z += ea1[c] * vv.z; acc1.w += ea1[c] * vv.w;
                }
            }
            __syncthreads();
        }
    }

    if (PASS == 0) {
        // combine (m,s) across the 32 j-lanes sharing an i-set
#pragma unroll
        for (int r = 0; r < 4; ++r) {
            float m = m_run[r], s = s_run[r];
#pragma unroll
            for (int off = 1; off < 32; off <<= 1) {
                const float m2 = __shfl_xor(m, off);
                const float s2 = __shfl_xor(s, off);
                const float mn = fmaxf(m, m2);
                s = s * __expf(m - mn) + s2 * __expf(m2 - mn);
                m = mn;
            }
            m_run[r] = m; s_run[r] = s;
        }
        if (jg == 0) {
#pragma unroll
            for (int r = 0; r < 4; ++r) {
                const int i = i0 + ig * 4 + r;
                m_arr[(size_t)bh * N_ + i] = m_run[r];
                s_arr[(size_t)bh * N_ + i] = s_run[r];
            }
        }
    } else {
        // ---- + bucket_sums @ w_rpe_v, write pre ----
        float4 rv0 = {0.f, 0.f, 0.f, 0.f}, rv1 = {0.f, 0.f, 0.f, 0.f};
        for (int u = 0; u < NB_; ++u) {
            const float4 wv = *(const float4*)&w_rpe_v[u * HD_ + dq * 4];
            const float b0 = bkt[(ih * 2 + 0) * 50 + u];
            const float b1 = bkt[(ih * 2 + 1) * 50 + u];
            rv0.x += b0 * wv.x; rv0.y += b0 * wv.y; rv0.z += b0 * wv.z; rv0.w += b0 * wv.w;
            rv1.x += b1 * wv.x; rv1.y += b1 * wv.y; rv1.z += b1 * wv.z; rv1.w += b1 * wv.w;
        }
        const int i_a = i0 + ih * 2, i_b = i_a + 1;
        float4 o0 = {acc0.x + rv0.x, acc0.y + rv0.y, acc0.z + rv0.z, acc0.w + rv0.w};
        float4 o1 = {acc1.x + rv1.x, acc1.y + rv1.y, acc1.z + rv1.z, acc1.w + rv1.w};
        *(float4*)&pre[((size_t)(b * N_ + i_a)) * C_ + h * HD_ + dq * 4] = o0;
        *(float4*)&pre[((size_t)(b * N_ + i_b)) * C_ + h * HD_ + dq * 4] = o1;
    }
}

// ---------------------------------------------------------------------------
// K5: projection GEMM: out[m,n] = sum_k pre[m,k] * proj_w[n,k] + bias[n]
// ---------------------------------------------------------------------------
__global__ void irpe_proj_gemm_k(const float* __restrict__ A, const float* __restrict__ Bw,
                                 const float* __restrict__ bias, float* __restrict__ Cout) {
    const int bm = blockIdx.x * 64, bn = blockIdx.y * 64;
    __shared__ float As[16][64];
    __shared__ float Bs[16][64];
    const int t = threadIdx.x;
    const int lr = t >> 2;
    const int lc = (t & 3) * 4;
    const int tx = t & 15, ty = t >> 4;
    float acc[4][4] = {{0.f}};

    for (int kt = 0; kt < C_; kt += 16) {
        const float4 av = *(const float4*)&A[(size_t)(bm + lr) * C_ + kt + lc];
        const float4 bv = *(const float4*)&Bw[(size_t)(bn + lr) * C_ + kt + lc];
        As[lc + 0][lr] = av.x; As[lc + 1][lr] = av.y; As[lc + 2][lr] = av.z; As[lc + 3][lr] = av.w;
        Bs[lc + 0][lr] = bv.x; Bs[lc + 1][lr] = bv.y; Bs[lc + 2][lr] = bv.z; Bs[lc + 3][lr] = bv.w;
        __syncthreads();
#pragma unroll
        for (int kk = 0; kk < 16; ++kk) {
            const float4 a = *(const float4*)&As[kk][ty * 4];
            const float4 b = *(const float4*)&Bs[kk][tx * 4];
            const float ar[4] = {a.x, a.y, a.z, a.w};
            const float br[4] = {b.x, b.y, b.z, b.w};
#pragma unroll
            for (int r = 0; r < 4; ++r)
#pragma unroll
                for (int c = 0; c < 4; ++c) acc[r][c] = fmaf(ar[r], br[c], acc[r][c]);
        }
        __syncthreads();
    }
#pragma unroll
    for (int r = 0; r < 4; ++r) {
        const int row = bm + ty * 4 + r;
#pragma unroll
        for (int c = 0; c < 4; ++c)
            Cout[(size_t)row * C_ + bn + tx * 4 + c] = acc[r][c] + bias[bn + tx * 4 + c];
    }
}

// ---------------------------------------------------------------------------
extern "C" void kernel_launch(void* const* d_in, const int* in_sizes, int n_in,
                              void* d_out, int out_size, void* d_ws, size_t ws_size,
                              hipStream_t stream) {
    const float* q       = (const float*)d_in[0];
    const float* k       = (const float*)d_in[1];
    const float* v       = (const float*)d_in[2];
    const float* w_rpe_q = (const float*)d_in[3];
    const float* w_rpe_k = (const float*)d_in[4];
    const float* w_rpe_v = (const float*)d_in[5];
    const float* proj_w  = (const float*)d_in[6];
    const float* proj_b  = (const float*)d_in[7];
    const int*   rp      = (const int*)d_in[8];

    float* out  = (float*)d_out;               // [B,N,C]
    float* attn = out + (size_t)B_ * N_ * C_;  // [B,H,N,N]

    char* ws = (char*)d_ws;
    float* tk    = (float*)ws; ws += (size_t)BH_ * N_ * NB_ * sizeof(float);
    float* tqT   = (float*)ws; ws += (size_t)BH_ * NB_ * N_ * sizeof(float);
    float* pre   = (float*)ws; ws += (size_t)B_ * N_ * C_ * sizeof(float);
    float* m_arr = (float*)ws; ws += (size_t)BH_ * N_ * sizeof(float);
    float* s_arr = (float*)ws; ws += (size_t)BH_ * N_ * sizeof(float);
    int*   lut   = (int*)ws;   ws += 64 * sizeof(int);

    irpe_lut_k<<<1, 64, 0, stream>>>(rp, lut);
    irpe_rpe_tables_k<<<dim3(N_ / 4, BH_), 256, 0, stream>>>(q, k, w_rpe_q, w_rpe_k, tk, tqT);

    const int nblk = BH_ * (N_ / TI_);  // 96*32 = 3072; bh = gid%96 pins bh to XCD
    irpe_attn_fused_k<0><<<nblk, 256, LDS_A_FLOATS * sizeof(float), stream>>>(
        q, k, v, tk, tqT, lut, m_arr, s_arr, attn, w_rpe_v, pre);
    irpe_attn_fused_k<1><<<nblk, 256, LDS_B_FLOATS * sizeof(float), stream>>>(
        q, k, v, tk, tqT, lut, m_arr, s_arr, attn, w_rpe_v, pre);

    irpe_proj_gemm_k<<<dim3((B_ * N_) / 64, C_ / 64), 256, 0, stream>>>(pre, proj_w, proj_b, out);
}

// Round 3
// 1220.709 us; speedup vs baseline: 3.9408x; 1.5784x over previous
//
#include <hip/hip_runtime.h>

#define B_ 8
#define N_ 1024
#define C_ 768
#define H_ 12
#define HD_ 64
#define NB_ 49
#define BH_ 96
#define SCALE_ 0.125f

typedef unsigned int u32;
typedef unsigned short u16;
typedef __attribute__((ext_vector_type(8))) short mfrag;   // 8 bf16 (4 VGPRs)
typedef __attribute__((ext_vector_type(4))) float f32x4;

__device__ __forceinline__ u16 f2bf(float x) {             // f32 -> bf16 (RNE)
    u32 u = __float_as_uint(x);
    u32 r = u + 0x7FFFu + ((u >> 16) & 1u);
    return (u16)(r >> 16);
}
__device__ __forceinline__ float bf2f(u16 h) { return __uint_as_float(((u32)h) << 16); }

// iRPE piecewise bucket (closed form for ALPHA=1.9, BETA=3.8, GAMMA=15.2):
// |d|: 0->0, 1->1, 2->2, 3->2, >=4->3 ; bucket = 3 + sign(d)*g
__device__ __forceinline__ int lutf(int d) {
    int a = d < 0 ? -d : d;
    int gg = (a < 2 ? a : 2) + (a >= 4 ? 1 : 0);
    return d < 0 ? 3 - gg : 3 + gg;
}

// ---------------------------------------------------------------------------
// K0a: split q,k into per-head bf16 hi/lo buffers [bh][n][64]
// ---------------------------------------------------------------------------
__global__ void irpe_split_qk_k(const float* __restrict__ q, const float* __restrict__ k,
                                u16* __restrict__ qh, u16* __restrict__ ql,
                                u16* __restrict__ kh, u16* __restrict__ kl) {
    const int tid = blockIdx.x * 256 + threadIdx.x;   // 96*1024*16 threads
    const int o = tid * 4;
    const int bh = o >> 16, rem = o & 65535;
    const int n = rem >> 6, d = rem & 63;
    const int b = bh / H_, h = bh % H_;
    const size_t src = ((size_t)(b * N_ + n)) * C_ + h * HD_ + d;
    const float4 qv = *(const float4*)&q[src];
    const float4 kv = *(const float4*)&k[src];
    ushort4 a, c;
    a = make_ushort4(f2bf(qv.x), f2bf(qv.y), f2bf(qv.z), f2bf(qv.w));
    c = make_ushort4(f2bf(qv.x - bf2f(a.x)), f2bf(qv.y - bf2f(a.y)),
                     f2bf(qv.z - bf2f(a.z)), f2bf(qv.w - bf2f(a.w)));
    *(ushort4*)&qh[o] = a;
    *(ushort4*)&ql[o] = c;
    a = make_ushort4(f2bf(kv.x), f2bf(kv.y), f2bf(kv.z), f2bf(kv.w));
    c = make_ushort4(f2bf(kv.x - bf2f(a.x)), f2bf(kv.y - bf2f(a.y)),
                     f2bf(kv.z - bf2f(a.z)), f2bf(kv.w - bf2f(a.w)));
    *(ushort4*)&kh[o] = a;
    *(ushort4*)&kl[o] = c;
}

// ---------------------------------------------------------------------------
// K0b: v -> transposed bf16 hi/lo [bh][64(d)][1024(j)]
// ---------------------------------------------------------------------------
__global__ void irpe_vt_k(const float* __restrict__ v,
                          u16* __restrict__ vth, u16* __restrict__ vtl) {
    __shared__ float tile[64][65];
    const int bh = blockIdx.y, jc0 = blockIdx.x * 64;
    const int b = bh / H_, h = bh % H_;
    const int t = threadIdx.x;
#pragma unroll
    for (int rep = 0; rep < 4; ++rep) {
        const int fl = rep * 256 + t;
        const int jr = fl >> 4, c4 = (fl & 15) * 4;
        const float4 x = *(const float4*)&v[((size_t)(b * N_ + jc0 + jr)) * C_ + h * HD_ + c4];
        tile[jr][c4] = x.x; tile[jr][c4 + 1] = x.y; tile[jr][c4 + 2] = x.z; tile[jr][c4 + 3] = x.w;
    }
    __syncthreads();
    const int d = t >> 2, jq = (t & 3) * 16;
    u32 ph[8], pl[8];
#pragma unroll
    for (int jj = 0; jj < 8; ++jj) {
        const float x0 = tile[jq + jj * 2][d], x1 = tile[jq + jj * 2 + 1][d];
        const u16 h0 = f2bf(x0), h1 = f2bf(x1);
        const float r0 = x0 - bf2f(h0), r1 = x1 - bf2f(h1);
        ph[jj] = (u32)h0 | ((u32)h1 << 16);
        pl[jj] = (u32)f2bf(r0) | ((u32)f2bf(r1) << 16);
    }
    const size_t dst = (((size_t)bh * 64 + d) << 10) + jc0 + jq;
    *(uint4*)&vth[dst] = make_uint4(ph[0], ph[1], ph[2], ph[3]);
    *(uint4*)&vth[dst + 8] = make_uint4(ph[4], ph[5], ph[6], ph[7]);
    *(uint4*)&vtl[dst] = make_uint4(pl[0], pl[1], pl[2], pl[3]);
    *(uint4*)&vtl[dst + 8] = make_uint4(pl[4], pl[5], pl[6], pl[7]);
}

// ---------------------------------------------------------------------------
// K2: RPE tables. tk[bh][i][49] ; tqT[bh][49][1024] (pre-scaled)
// ---------------------------------------------------------------------------
__global__ void irpe_rpe_tables_k(const float* __restrict__ q, const float* __restrict__ k,
                                  const float* __restrict__ w_rpe_q, const float* __restrict__ w_rpe_k,
                                  float* __restrict__ tk, float* __restrict__ tqT) {
    const int bh = blockIdx.y, b = bh / H_, h = bh % H_;
    const int row0 = blockIdx.x * 4;
    __shared__ float qs[4][HD_], ks[4][HD_];
    const int t = threadIdx.x;
    {
        const int r = t >> 6, d = t & 63;
        const size_t gi = ((size_t)(b * N_ + row0 + r)) * C_ + h * HD_ + d;
        qs[r][d] = q[gi];
        ks[r][d] = k[gi];
    }
    __syncthreads();
    if (t < 4 * NB_) {
        const int r = t / NB_, u = t - r * NB_;
        float dk = 0.f, dq = 0.f;
#pragma unroll
        for (int d = 0; d < HD_; ++d) {
            dk = fmaf(qs[r][d], w_rpe_k[d * NB_ + u], dk);
            dq = fmaf(ks[r][d], w_rpe_q[d * NB_ + u], dq);
        }
        tk[((size_t)bh * N_ + row0 + r) * NB_ + u] = dk;
        tqT[(((size_t)bh * NB_ + u) << 10) + row0 + r] = dq * SCALE_;
    }
}

// ---------------------------------------------------------------------------
// K_main: single-sweep fused attention with bf16x3 MFMA.
// Block = (bh, 32 i-rows = one yi row). 256 thr = 4 waves.
// Wave w: mt=w&1 (16-row M-tile), pair=(w>>1): QK j-tiles {2p,2p+1}, PV d-tiles same.
// Chunk = 64 j-cols. e written UNNORMALIZED to attn; PV/buckets normalized here;
// attn normalized by irpe_rescale_k.
// ---------------------------------------------------------------------------
__global__ __launch_bounds__(256, 3) void irpe_attn_mfma_k(
    const u16* __restrict__ qh_g, const u16* __restrict__ ql_g,
    const u16* __restrict__ kh_g, const u16* __restrict__ kl_g,
    const u16* __restrict__ vth_g, const u16* __restrict__ vtl_g,
    const float* __restrict__ tk, const float* __restrict__ tqT,
    const float* __restrict__ w_rpe_v,
    float* __restrict__ attn, float* __restrict__ s_arr, float* __restrict__ pre) {
    __shared__ u16 qbh[2048], qbl[2048];   // [32][64] swizzled
    __shared__ u16 kvh[4096], kvl[4096];   // [64][64] swizzled (k, then vT)
    __shared__ u16 awh[2048], awl[2048];   // e hi/lo [32][64] swizzled
    __shared__ float tks_s[1600];          // [32][50]
    __shared__ float bkt_s[1600];          // [32][50]
    __shared__ float ssum_s[32];

    const int gid = blockIdx.x;
    const int bh = gid % BH_, itile = gid / BH_;   // bh%8 pins XCD
    const int b = bh / H_, h = bh % H_;
    const int i0 = itile * 32;
    const int yi = itile;                          // all 32 rows share yi; xi == local row
    const int t = threadIdx.x;
    const int w = t >> 6, lane = t & 63;
    const int g = lane >> 4, lh = lane & 15;
    const int mt = w & 1;
    const int jt0 = (w >> 1) * 2;

    {   // stage q tile (hi+lo)
        const int row = t >> 3, un = t & 7;
        const size_t gsrc = ((((size_t)bh << 10) + i0 + row) << 6) + un * 8;
        const int ldso = row * 128 + ((un ^ (row & 7)) << 4);
        *(mfrag*)((char*)qbh + ldso) = *(const mfrag*)&qh_g[gsrc];
        *(mfrag*)((char*)qbl + ldso) = *(const mfrag*)&ql_g[gsrc];
    }
    for (int idx = t; idx < 32 * 49; idx += 256) {
        const int row = idx / 49, u = idx - row * 49;
        tks_s[row * 50 + u] = tk[(((size_t)bh << 10) + i0 + row) * 49 + u];
    }
    for (int idx = t; idx < 1600; idx += 256) bkt_s[idx] = 0.f;
    if (t < 32) ssum_s[t] = 0.f;

    f32x4 apv0 = {0.f, 0.f, 0.f, 0.f}, apv1 = {0.f, 0.f, 0.f, 0.f};
    float srow[4] = {0.f, 0.f, 0.f, 0.f};
    const size_t tqbase = (size_t)bh * 49 * 1024;
    const size_t attnrow0 = ((size_t)bh << 10) + i0;

    for (int ch = 0; ch < 16; ++ch) {
        const int jc0 = ch * 64;
        // ---- stage K chunk ----
#pragma unroll
        for (int rep = 0; rep < 2; ++rep) {
            const int unit = rep * 256 + t;
            const int row = unit >> 3, un = unit & 7;
            const size_t gsrc = ((((size_t)bh << 10) + jc0 + row) << 6) + un * 8;
            const int ldso = row * 128 + ((un ^ (row & 7)) << 4);
            *(mfrag*)((char*)kvh + ldso) = *(const mfrag*)&kh_g[gsrc];
            *(mfrag*)((char*)kvl + ldso) = *(const mfrag*)&kl_g[gsrc];
        }
        __syncthreads();

        // ---- QK (bf16x3) ----
        f32x4 aq[2];
        {
            const int ra = mt * 16 + lh, sw = ra & 7;
            const mfrag ah0 = *(const mfrag*)((const char*)qbh + ra * 128 + ((g ^ sw) << 4));
            const mfrag al0 = *(const mfrag*)((const char*)qbl + ra * 128 + ((g ^ sw) << 4));
            const mfrag ah1 = *(const mfrag*)((const char*)qbh + ra * 128 + (((4 + g) ^ sw) << 4));
            const mfrag al1 = *(const mfrag*)((const char*)qbl + ra * 128 + (((4 + g) ^ sw) << 4));
#pragma unroll
            for (int ji = 0; ji < 2; ++ji) {
                const int rb = (jt0 + ji) * 16 + lh, swb = rb & 7;
                const mfrag bh0 = *(const mfrag*)((const char*)kvh + rb * 128 + ((g ^ swb) << 4));
                const mfrag bl0 = *(const mfrag*)((const char*)kvl + rb * 128 + ((g ^ swb) << 4));
                const mfrag bh1 = *(const mfrag*)((const char*)kvh + rb * 128 + (((4 + g) ^ swb) << 4));
                const mfrag bl1 = *(const mfrag*)((const char*)kvl + rb * 128 + (((4 + g) ^ swb) << 4));
                f32x4 c = {0.f, 0.f, 0.f, 0.f};
                c = __builtin_amdgcn_mfma_f32_16x16x32_bf16(ah0, bh0, c, 0, 0, 0);
                c = __builtin_amdgcn_mfma_f32_16x16x32_bf16(ah0, bl0, c, 0, 0, 0);
                c = __builtin_amdgcn_mfma_f32_16x16x32_bf16(al0, bh0, c, 0, 0, 0);
                c = __builtin_amdgcn_mfma_f32_16x16x32_bf16(ah1, bh1, c, 0, 0, 0);
                c = __builtin_amdgcn_mfma_f32_16x16x32_bf16(ah1, bl1, c, 0, 0, 0);
                c = __builtin_amdgcn_mfma_f32_16x16x32_bf16(al1, bh1, c, 0, 0, 0);
                aq[ji] = c;
            }
        }
        __syncthreads();   // all QK reads of kv done

        // ---- issue V-stage loads (regs) ----
        mfrag vstg[4];
#pragma unroll
        for (int rep = 0; rep < 2; ++rep) {
            const int unit = rep * 256 + t;
            const int row = unit >> 3, un = unit & 7;
            const size_t gsrc = (((size_t)bh * 64 + row) << 10) + jc0 + un * 8;
            vstg[rep * 2] = *(const mfrag*)&vth_g[gsrc];
            vstg[rep * 2 + 1] = *(const mfrag*)&vtl_g[gsrc];
        }

        // ---- bias + exp + emit (acc layout: row=(g*4+r), col=lh) ----
#pragma unroll
        for (int ji = 0; ji < 2; ++ji) {
            const int jl = (jt0 + ji) * 16 + lh;
            const int j = jc0 + jl;
            const int yj = j >> 5, xj = j & 31;
            const int by = lutf(yi - yj);
#pragma unroll
            for (int r = 0; r < 4; ++r) {
                const int xi = mt * 16 + g * 4 + r;
                const int bij = by * 7 + lutf(xi - xj);
                const float tks_v = tks_s[xi * 50 + bij];
                const float tq_v = tqT[tqbase + ((size_t)(48 - bij) << 10) + j];
                const float e = __expf(aq[ji][r] * SCALE_ + tks_v + tq_v);
                srow[r] += e;
                atomicAdd(&bkt_s[xi * 50 + bij], e);
                attn[((attnrow0 + xi) << 10) + j] = e;
                const u16 eh = f2bf(e);
                const u16 el = f2bf(e - bf2f(eh));
                const int off = xi * 128 + ((jl * 2) ^ ((xi & 7) << 4));
                *(u16*)((char*)awh + off) = eh;
                *(u16*)((char*)awl + off) = el;
            }
        }

        // ---- write V stage to LDS (kv buffers now free) ----
#pragma unroll
        for (int rep = 0; rep < 2; ++rep) {
            const int unit = rep * 256 + t;
            const int row = unit >> 3, un = unit & 7;
            const int ldso = row * 128 + ((un ^ (row & 7)) << 4);
            *(mfrag*)((char*)kvh + ldso) = vstg[rep * 2];
            *(mfrag*)((char*)kvl + ldso) = vstg[rep * 2 + 1];
        }
        __syncthreads();   // vT staged + arow written

        // ---- PV (bf16x3): out[i][d] += e[i][j] * v[j][d] ----
        {
            const int ra = mt * 16 + lh, sw = ra & 7;
            const mfrag pah0 = *(const mfrag*)((const char*)awh + ra * 128 + ((g ^ sw) << 4));
            const mfrag pal0 = *(const mfrag*)((const char*)awl + ra * 128 + ((g ^ sw) << 4));
            const mfrag pah1 = *(const mfrag*)((const char*)awh + ra * 128 + (((4 + g) ^ sw) << 4));
            const mfrag pal1 = *(const mfrag*)((const char*)awl + ra * 128 + (((4 + g) ^ sw) << 4));
#pragma unroll
            for (int di = 0; di < 2; ++di) {
                const int rv = (jt0 + di) * 16 + lh, swv = rv & 7;
                const mfrag vh0 = *(const mfrag*)((const char*)kvh + rv * 128 + ((g ^ swv) << 4));
                const mfrag vl0 = *(const mfrag*)((const char*)kvl + rv * 128 + ((g ^ swv) << 4));
                const mfrag vh1 = *(const mfrag*)((const char*)kvh + rv * 128 + (((4 + g) ^ swv) << 4));
                const mfrag vl1 = *(const mfrag*)((const char*)kvl + rv * 128 + (((4 + g) ^ swv) << 4));
                f32x4 c = di ? apv1 : apv0;
                c = __builtin_amdgcn_mfma_f32_16x16x32_bf16(pah0, vh0, c, 0, 0, 0);
                c = __builtin_amdgcn_mfma_f32_16x16x32_bf16(pah0, vl0, c, 0, 0, 0);
                c = __builtin_amdgcn_mfma_f32_16x16x32_bf16(pal0, vh0, c, 0, 0, 0);
                c = __builtin_amdgcn_mfma_f32_16x16x32_bf16(pah1, vh1, c, 0, 0, 0);
                c = __builtin_amdgcn_mfma_f32_16x16x32_bf16(pah1, vl1, c, 0, 0, 0);
                c = __builtin_amdgcn_mfma_f32_16x16x32_bf16(pal1, vh1, c, 0, 0, 0);
                if (di) apv1 = c; else apv0 = c;
            }
        }
        __syncthreads();   // arow/kv free for next chunk
    }

    // ---- epilogue: row sums, rpe_v, normalize, write ----
#pragma unroll
    for (int r = 0; r < 4; ++r) {
        float s = srow[r];
        s += __shfl_xor(s, 1); s += __shfl_xor(s, 2);
        s += __shfl_xor(s, 4); s += __shfl_xor(s, 8);
        if (lh == 0) atomicAdd(&ssum_s[mt * 16 + g * 4 + r], s);
    }
    __syncthreads();
    if (t < 32) s_arr[((size_t)bh << 10) + i0 + t] = ssum_s[t];

    f32x4 rpe0 = {0.f, 0.f, 0.f, 0.f}, rpe1 = {0.f, 0.f, 0.f, 0.f};
    const int d0 = jt0 * 16 + lh;
    for (int u = 0; u < 49; ++u) {
        const float wv0 = w_rpe_v[u * 64 + d0];
        const float wv1 = w_rpe_v[u * 64 + 16 + d0];
#pragma unroll
        for (int r = 0; r < 4; ++r) {
            const float bv = bkt_s[(mt * 16 + g * 4 + r) * 50 + u];
            rpe0[r] += bv * wv0;
            rpe1[r] += bv * wv1;
        }
    }
#pragma unroll
    for (int r = 0; r < 4; ++r) {
        const int row = mt * 16 + g * 4 + r;
        const float inv = 1.0f / ssum_s[row];
        const size_t obase = ((size_t)(b * N_ + i0 + row)) * C_ + h * HD_;
        pre[obase + d0] = (apv0[r] + rpe0[r]) * inv;
        pre[obase + 16 + d0] = (apv1[r] + rpe1[r]) * inv;
    }
}

// ---------------------------------------------------------------------------
// K4: normalize attn rows by 1/rowsum
// ---------------------------------------------------------------------------
__global__ void irpe_rescale_k(float* __restrict__ attn, const float* __restrict__ s_arr) {
    const int bh = blockIdx.y;
    const int i = blockIdx.x * 4 + (threadIdx.x >> 6);
    const int lane = threadIdx.x & 63;
    const float inv = 1.0f / s_arr[((size_t)bh << 10) + i];
    float4* row = (float4*)&attn[((((size_t)bh << 10) + i) << 10)];
#pragma unroll
    for (int qd = 0; qd < 4; ++qd) {
        float4 x = row[lane + qd * 64];
        x.x *= inv; x.y *= inv; x.z *= inv; x.w *= inv;
        row[lane + qd * 64] = x;
    }
}

// ---------------------------------------------------------------------------
// K5: projection GEMM (f32): out[m,n] = pre[m,:] . proj_w[n,:] + bias[n]
// ---------------------------------------------------------------------------
__global__ void irpe_proj_gemm_k(const float* __restrict__ A, const float* __restrict__ Bw,
                                 const float* __restrict__ bias, float* __restrict__ Cout) {
    const int bm = blockIdx.x * 64, bn = blockIdx.y * 64;
    __shared__ float As[16][64];
    __shared__ float Bs[16][64];
    const int t = threadIdx.x;
    const int lr = t >> 2;
    const int lc = (t & 3) * 4;
    const int tx = t & 15, ty = t >> 4;
    float acc[4][4] = {{0.f}};

    for (int kt = 0; kt < C_; kt += 16) {
        const float4 av = *(const float4*)&A[(size_t)(bm + lr) * C_ + kt + lc];
        const float4 bv = *(const float4*)&Bw[(size_t)(bn + lr) * C_ + kt + lc];
        As[lc + 0][lr] = av.x; As[lc + 1][lr] = av.y; As[lc + 2][lr] = av.z; As[lc + 3][lr] = av.w;
        Bs[lc + 0][lr] = bv.x; Bs[lc + 1][lr] = bv.y; Bs[lc + 2][lr] = bv.z; Bs[lc + 3][lr] = bv.w;
        __syncthreads();
#pragma unroll
        for (int kk = 0; kk < 16; ++kk) {
            const float4 a = *(const float4*)&As[kk][ty * 4];
            const float4 b = *(const float4*)&Bs[kk][tx * 4];
            const float ar[4] = {a.x, a.y, a.z, a.w};
            const float br[4] = {b.x, b.y, b.z, b.w};
#pragma unroll
            for (int r = 0; r < 4; ++r)
#pragma unroll
                for (int c = 0; c < 4; ++c) acc[r][c] = fmaf(ar[r], br[c], acc[r][c]);
        }
        __syncthreads();
    }
#pragma unroll
    for (int r = 0; r < 4; ++r) {
        const int rowi = bm + ty * 4 + r;
#pragma unroll
        for (int c = 0; c < 4; ++c)
            Cout[(size_t)rowi * C_ + bn + tx * 4 + c] = acc[r][c] + bias[bn + tx * 4 + c];
    }
}

// ---------------------------------------------------------------------------
extern "C" void kernel_launch(void* const* d_in, const int* in_sizes, int n_in,
                              void* d_out, int out_size, void* d_ws, size_t ws_size,
                              hipStream_t stream) {
    const float* q       = (const float*)d_in[0];
    const float* k       = (const float*)d_in[1];
    const float* v       = (const float*)d_in[2];
    const float* w_rpe_q = (const float*)d_in[3];
    const float* w_rpe_k = (const float*)d_in[4];
    const float* w_rpe_v = (const float*)d_in[5];
    const float* proj_w  = (const float*)d_in[6];
    const float* proj_b  = (const float*)d_in[7];

    float* out  = (float*)d_out;               // [B,N,C]
    float* attn = out + (size_t)B_ * N_ * C_;  // [B,H,N,N]

    char* ws = (char*)d_ws;
    float* tk    = (float*)ws; ws += (size_t)BH_ * N_ * NB_ * 4;
    float* tqT   = (float*)ws; ws += (size_t)BH_ * NB_ * N_ * 4;
    float* pre   = (float*)ws; ws += (size_t)B_ * N_ * C_ * 4;
    float* s_arr = (float*)ws; ws += (size_t)BH_ * N_ * 4;
    u16* qh  = (u16*)ws; ws += (size_t)BH_ * N_ * 64 * 2;
    u16* ql  = (u16*)ws; ws += (size_t)BH_ * N_ * 64 * 2;
    u16* kh  = (u16*)ws; ws += (size_t)BH_ * N_ * 64 * 2;
    u16* kl  = (u16*)ws; ws += (size_t)BH_ * N_ * 64 * 2;
    u16* vth = (u16*)ws; ws += (size_t)BH_ * 64 * N_ * 2;
    u16* vtl = (u16*)ws; ws += (size_t)BH_ * 64 * N_ * 2;

    irpe_split_qk_k<<<6144, 256, 0, stream>>>(q, k, qh, ql, kh, kl);
    irpe_vt_k<<<dim3(16, BH_), 256, 0, stream>>>(v, vth, vtl);
    irpe_rpe_tables_k<<<dim3(N_ / 4, BH_), 256, 0, stream>>>(q, k, w_rpe_q, w_rpe_k, tk, tqT);

    irpe_attn_mfma_k<<<BH_ * (N_ / 32), 256, 0, stream>>>(
        qh, ql, kh, kl, vth, vtl, tk, tqT, w_rpe_v, attn, s_arr, pre);

    irpe_rescale_k<<<dim3(N_ / 4, BH_), 256, 0, stream>>>(attn, s_arr);
    irpe_proj_gemm_k<<<dim3((B_ * N_) / 64, C_ / 64), 256, 0, stream>>>(pre, proj_w, proj_b, out);
}